// Round 1
// baseline (68.566 us; speedup 1.0000x reference)
//
#include <hip/hip_runtime.h>
#include <hip/hip_bf16.h>
#include <math.h>

// Problem constants (fixed by reference setup_inputs)
#define B_SZ 64
#define N_IN 1024
#define IDIM 64
#define NC   16
#define DC   32

// Workspace layout (in floats)
//  xsum : [64][64]        @ 0        (zeroed, atomic-accumulated)
//  xs1  : [64][16][64]    @ 4096     (zeroed, atomic-accumulated)
//  xs2  : [64][16][64]    @ 69632    (zeroed, atomic-accumulated)
//  wv   : [64][16][64]    @ 135168   (fully written before each read)
//  blog : [64][16][1024]  @ 200704   (fully written by pass1 before pass2 reads)
#define WS_XSUM 0
#define WS_XS1  4096
#define WS_XS2  69632
#define WS_WV   135168
#define WS_BLOG 200704
#define WS_ZERO_FLOATS 135168   // zero xsum+xs1+xs2 each call

__device__ __forceinline__ float rdlane(float v, int l) {
    return __int_as_float(__builtin_amdgcn_readlane(__float_as_int(v), l));
}

// -------- Kernel 1: column sums of x per batch: xsum[b][i] = sum_n x[b,n,i]
__global__ __launch_bounds__(256) void k_colsum(const float* __restrict__ x,
                                                float* __restrict__ xsum) {
    const int b = blockIdx.y, chunk = blockIdx.x;          // 8 chunks of 128 rows
    const int i = threadIdx.x & 63, p = threadIdx.x >> 6;  // 4-way row split
    const float* xb = x + (size_t)(b * N_IN + chunk * 128) * IDIM;
    float s = 0.f;
    for (int r = p; r < 128; r += 4) s += xb[r * IDIM + i];  // coalesced 1KB/instr
    atomicAdd(&xsum[b * IDIM + i], s);
}

// -------- Kernel 2 (tiny, per (b,c) wave): s = scale * src @ W[c]; v = squash(s);
// then either wv[i] = W[c] @ v  (WRITE_OUT=false) or write v to output.
template<bool WRITE_OUT>
__global__ __launch_bounds__(64) void k_caps(const float* __restrict__ src,
                                             const float* __restrict__ W,
                                             float* __restrict__ out,
                                             float scale, int b_stride, int c_stride) {
    const int b = blockIdx.y, c = blockIdx.x;
    const int lane = threadIdx.x;      // 0..63, one wave
    const int d = lane & 31;           // lanes 32..63 duplicate lanes 0..31
    const float* sv = src + b * b_stride + c * c_stride;   // 64 floats (uniform -> s_loads)
    const float* Wc = W + c * IDIM * DC;
    float s = 0.f;
#pragma unroll 8
    for (int i = 0; i < IDIM; i++) s += sv[i] * Wc[i * DC + d];
    s *= scale;
    // norm^2 across the 32 d-lanes (both halves reduce identically)
    float n2 = s * s;
#pragma unroll
    for (int m = 16; m >= 1; m >>= 1) n2 += __shfl_xor(n2, m, 64);
    const float nr = sqrtf(n2);
    const float v = (n2 / (1.f + n2)) * s / (nr + 1e-8f);
    if (WRITE_OUT) {
        if (lane < 32) out[(b * NC + c) * DC + d] = v;
        return;
    }
    __shared__ float vsh[DC];
    if (lane < 32) vsh[d] = v;
    __syncthreads();
    float w = 0.f;
#pragma unroll 8
    for (int d2 = 0; d2 < DC; d2++) w += Wc[lane * DC + d2] * vsh[d2];
    out[(b * NC + c) * IDIM + lane] = w;   // wv[b][c][i]
}

// -------- Kernel 3 (heavy): per (b, 128-row n-chunk):
//   a[c] = x[n] . wv[b,c]          (agreement)
//   b-logits update (+ store pass1 / load pass2), softmax over c in-register
//   xs[b,c,i] += cw[c,n] * x[n,i]  (atomic accumulate)
template<int ITER>
__global__ __launch_bounds__(128) void k_route(const float* __restrict__ x,
                                               const float* __restrict__ wv,
                                               float* __restrict__ blog,
                                               float* __restrict__ xs) {
    const int b = blockIdx.y, chunk = blockIdx.x;
    const int n0 = chunk * 128;
    const int tid = threadIdx.x, lane = tid & 63, wave = tid >> 6;

    // x-chunk transposed in LDS with diagonal skew: element (n_local, i) at
    // xT[i*128 + ((n_local + i) & 127)] -> conflict-free for both access patterns.
    __shared__ float xT[64 * 128];   // 32 KB

    // Phase 1: coalesced load + skewed store
    const float4* xb4 = reinterpret_cast<const float4*>(x + (size_t)(b * N_IN + n0) * IDIM);
#pragma unroll
    for (int k = 0; k < 16; k++) {
        int f = k * 128 + tid;              // 2048 float4 total
        float4 v4 = xb4[f];
        int nl = f >> 4, i0 = (f & 15) * 4;
        float vv[4] = {v4.x, v4.y, v4.z, v4.w};
#pragma unroll
        for (int j = 0; j < 4; j++) {
            int i = i0 + j;
            xT[i * 128 + ((nl + i) & 127)] = vv[j];
        }
    }
    __syncthreads();

    // Phase 2: one thread per n. a[c] = sum_i x[n,i]*wv[c,i]
    const float* wvb = wv + b * NC * IDIM;  // uniform indices -> scalar loads
    float a[NC];
#pragma unroll
    for (int c = 0; c < NC; c++) a[c] = 0.f;
#pragma unroll 4
    for (int i = 0; i < IDIM; i++) {
        float xv = xT[i * 128 + ((tid + i) & 127)];
#pragma unroll
        for (int c = 0; c < NC; c++) a[c] += xv * wvb[c * IDIM + i];
    }
    const int n = n0 + tid;
    float* bl = blog + b * NC * N_IN;
    if (ITER == 2) {
#pragma unroll
        for (int c = 0; c < NC; c++) a[c] += bl[c * N_IN + n];
    } else {
#pragma unroll
        for (int c = 0; c < NC; c++) bl[c * N_IN + n] = a[c];
    }
    // softmax over the 16 capsules, in registers
    float mx = a[0];
#pragma unroll
    for (int c = 1; c < NC; c++) mx = fmaxf(mx, a[c]);
    float ssum = 0.f;
#pragma unroll
    for (int c = 0; c < NC; c++) { a[c] = __expf(a[c] - mx); ssum += a[c]; }
    const float inv = 1.f / ssum;
#pragma unroll
    for (int c = 0; c < NC; c++) a[c] *= inv;   // a[] is now cw for this n

    // Phase 3: lane = i. Wave w covers n_local in [w*64, w*64+64); the cw for
    // those n live in this wave's lanes -> readlane broadcast (scalar operand).
    float acc[NC];
#pragma unroll
    for (int c = 0; c < NC; c++) acc[c] = 0.f;
    for (int nl = 0; nl < 64; nl++) {
        int ng = wave * 64 + nl;
        float xv = xT[lane * 128 + ((ng + lane) & 127)];
#pragma unroll
        for (int c = 0; c < NC; c++) acc[c] += rdlane(a[c], nl) * xv;
    }
    float* xsb = xs + b * NC * IDIM;
#pragma unroll
    for (int c = 0; c < NC; c++) atomicAdd(&xsb[c * IDIM + lane], acc[c]);
}

extern "C" void kernel_launch(void* const* d_in, const int* in_sizes, int n_in,
                              void* d_out, int out_size, void* d_ws, size_t ws_size,
                              hipStream_t stream) {
    const float* x = (const float*)d_in[0];    // [64,1024,64]
    const float* W = (const float*)d_in[1];    // [16,64,32]
    float* out = (float*)d_out;                // [64,16,32]
    float* ws = (float*)d_ws;

    float* xsum = ws + WS_XSUM;
    float* xs1  = ws + WS_XS1;
    float* xs2  = ws + WS_XS2;
    float* wv   = ws + WS_WV;
    float* blog = ws + WS_BLOG;

    hipMemsetAsync(ws, 0, WS_ZERO_FLOATS * sizeof(float), stream);

    // iter 0: c = 1/16 uniform -> s0 = (1/16) * colsum(x) @ W
    k_colsum<<<dim3(8, 64), 256, 0, stream>>>(x, xsum);
    k_caps<false><<<dim3(NC, B_SZ), 64, 0, stream>>>(xsum, W, wv, 1.f / 16.f, IDIM, 0);
    // iter 1: agreement vs v0, b1 = a, softmax, xs1
    k_route<1><<<dim3(8, 64), 128, 0, stream>>>(x, wv, blog, xs1);
    k_caps<false><<<dim3(NC, B_SZ), 64, 0, stream>>>(xs1, W, wv, 1.f, NC * IDIM, IDIM);
    // iter 2: agreement vs v1, b2 = b1 + a, softmax, xs2
    k_route<2><<<dim3(8, 64), 128, 0, stream>>>(x, wv, blog, xs2);
    // final squash -> output v
    k_caps<true><<<dim3(NC, B_SZ), 64, 0, stream>>>(xs2, W, out, 1.f, NC * IDIM, IDIM);
}